// Round 17
// baseline (411.461 us; speedup 1.0000x reference)
//
#include <hip/hip_runtime.h>

typedef unsigned short ushort_t;
typedef _Float16 f16x8 __attribute__((ext_vector_type(8)));
typedef float f32x4 __attribute__((ext_vector_type(4)));
typedef unsigned short u16x8 __attribute__((ext_vector_type(8)));

#define DEVINL __device__ __forceinline__

constexpr int B = 16, S = 512, F = 1024;
constexpr int M_ROWS = B * S;                    // 8192
constexpr size_t NX = (size_t)M_ROWS * F;        // 8,388,608 elems per modality
constexpr size_t NW = (size_t)F * (2 * F);       // 2,097,152 elems per branch

// ---------- fp16 helpers ----------
DEVINL ushort_t f2h(float f) { return __builtin_bit_cast(ushort_t, (_Float16)f); }
DEVINL float h2f(ushort_t h) { return (float)__builtin_bit_cast(_Float16, h); }

// ---------- async global->LDS (16B per lane) ----------
DEVINL void gload_lds16(const void* g, void* l) {
  __builtin_amdgcn_global_load_lds(
      (__attribute__((address_space(1))) void*)(g),
      (__attribute__((address_space(3))) void*)(l), 16, 0, 0);
}

DEVINL f32x4 mfma16h(f16x8 a, f16x8 b, f32x4 c) {
  return __builtin_amdgcn_mfma_f32_16x16x32_f16(a, b, c, 0, 0, 0);
}

// ================== B-in-register BK=64 core, BM=256 x BN=128 (feat) ==================
// LDS carries ONLY A (2 buffers x 32 KB); B-fragments load straight from
// global (L2-hot 512 KB panel) into VGPRs, double-buffered one tile ahead.
// Rationale (R16 accounting): per CU-tile the LDS pipe served 96 KB reads +
// 48 KB writes (1700 cyc) vs MFMA 1242 -> LDS-bound. Dropping B: A-only
// 64 KB reads + 32 KB writes = 1130 cyc < MFMA 1242 -> MFMA-bound.
// B lane address: rows wc+(lane&15), k-chunk (lane>>4)*8 — the 64 lanes cover
// 16 rows x 64 B fully (no line overfetch).
// Tile: {load Bnext (8 dwordx4) | read A (8 ds) | BAR | 16 MFMA j=0,1
// (consumes ALL A frags) | BAR | stage A(t+2) into CURRENT buf (safe: every
// wave's A reads were lgkm-retired before its MFMAs, barrier after -> all
// waves retired; R16 argument verbatim) | 16 MFMA j=2,3 | vmcnt(4) | BAR}.
// vmcnt(4) retires A(t+1)+Bnext (oldest 12-4=8+4... outstanding = A(t+1) 4 +
// Bnext 8 + A(t+2) 4; waits to 4 -> A(t+1),Bnext done, A(t+2) in flight —
// counted, never 0 (T4).
// NOTE (R8): never raise __launch_bounds__ min-waves; accumulator spills.
template <int KSTEPS, int SPLIT_STEP>
DEVINL void gemm_breg_core(const ushort_t* __restrict__ a1, const ushort_t* __restrict__ a2,
                           int lda, const ushort_t* __restrict__ bsrc, int ldb,
                           ushort_t* lds, int tid, f32x4 (&acc)[4][4]) {
  constexpr int BUF = 16384;   // A-only buffer (32 KB)
  constexpr int KM = KSTEPS - 1;
  const int lane = tid & 63, w = tid >> 6;
  const int wr = (w >> 1) * 64, wc = (w & 1) * 64;
  const int slog = (lane & 7) ^ ((lane >> 3) & 7);   // swizzled k-slot (staging)

  // hoisted ds_read bases (row + swizzled slot, k-subtile 0/1)
  const int sl0 = ((lane >> 4) ^ (lane & 7)) * 8;
  const int sl1 = ((4 + (lane >> 4)) ^ (lane & 7)) * 8;
  const ushort_t* dsA0 = lds + (wr + (lane & 15)) * 64 + sl0;
  const ushort_t* dsA1 = lds + (wr + (lane & 15)) * 64 + sl1;

  // hoisted gload bases
  const size_t ldaS = (size_t)lda, ldbS = (size_t)ldb;
  const ushort_t* gA1 = a1 + (size_t)(w * 16 + (lane >> 3)) * ldaS + slog * 8;
  const ushort_t* gA2 = a2 + (size_t)(w * 16 + (lane >> 3)) * ldaS + slog * 8;
  ushort_t* dA = lds + (w * 16) * 64;          // + bb*BUF + h*8192; HW adds lane*16B

  // B register-load base: lane covers row wc+(lane&15), 16B chunk (lane>>4)
  const ushort_t* gB = bsrc + (size_t)(wc + (lane & 15)) * ldbS + (lane >> 4) * 8;

  auto stA = [&](int bb, int ks, int h) {      // 128 rows per half, 2 gloads/wave
    const ushort_t* base = ((SPLIT_STEP >= KSTEPS) || (ks < SPLIT_STEP)) ? gA1 : gA2;
    const ushort_t* s = base + (ks & (SPLIT_STEP - 1)) * 64 + (size_t)(h * 128) * ldaS;
    ushort_t* d = dA + bb * BUF + h * 8192;
    gload_lds16(s, d);
    gload_lds16(s + 8 * ldaS, d + 512);
  };

#define BAR asm volatile("s_barrier" ::: "memory")
#define LDB(DST, T_) {                                               \
  const ushort_t* gb_ = gB + (size_t)((T_) & KM) * 64;               \
  _Pragma("unroll")                                                  \
  for (int j = 0; j < 4; ++j) {                                      \
    DST[j][0] = *(const f16x8*)(gb_ + (size_t)(j * 16) * ldbS);      \
    DST[j][1] = *(const f16x8*)(gb_ + (size_t)(j * 16) * ldbS + 32); \
  }                                                                  \
}
#define MMH(BC, J0)                                                  \
  __builtin_amdgcn_s_setprio(1);                                     \
  _Pragma("unroll")                                                  \
  for (int i = 0; i < 4; ++i) {                                      \
    acc[i][(J0)]     = mfma16h(rA[i][0], BC[(J0)][0], acc[i][(J0)]);         \
    acc[i][(J0)]     = mfma16h(rA[i][1], BC[(J0)][1], acc[i][(J0)]);         \
    acc[i][(J0) + 1] = mfma16h(rA[i][0], BC[(J0) + 1][0], acc[i][(J0) + 1]); \
    acc[i][(J0) + 1] = mfma16h(rA[i][1], BC[(J0) + 1][1], acc[i][(J0) + 1]); \
  }                                                                  \
  __builtin_amdgcn_s_setprio(0);
#define TILEB(BB, T, BCUR, BNXT) {                                   \
  LDB(BNXT, (T) + 1)                                                 \
  const int ksA = ((T) + 2) & KM;                                    \
  const ushort_t* rA0 = dsA0 + (BB) * BUF;                           \
  const ushort_t* rA1 = dsA1 + (BB) * BUF;                           \
  f16x8 rA[4][2];                                                    \
  _Pragma("unroll")                                                  \
  for (int i = 0; i < 4; ++i) {                                      \
    rA[i][0] = *(const f16x8*)(rA0 + i * 1024);                      \
    rA[i][1] = *(const f16x8*)(rA1 + i * 1024);                      \
  }                                                                  \
  BAR;                                                               \
  MMH(BCUR, 0)                                                       \
  BAR;                                                               \
  stA(BB, ksA, 0); stA(BB, ksA, 1);                                  \
  MMH(BCUR, 2)                                                       \
  asm volatile("s_waitcnt vmcnt(4)" ::: "memory");                   \
  BAR;                                                               \
}

  f16x8 B0[4][2], B1[4][2];
  // prologue: A(0) staged, B(0) to regs, A(1) staged; vmcnt(4) retires
  // A(0)+B(0) (oldest 12 of 16), leaves A(1) in flight (counted).
  stA(0, 0, 0); stA(0, 0, 1);
  LDB(B0, 0)
  stA(1, 1 & KM, 0); stA(1, 1 & KM, 1);
  asm volatile("s_waitcnt vmcnt(4)" ::: "memory");
  BAR;

  for (int t = 0; t < KSTEPS; t += 2) {
    TILEB(0, t, B0, B1)
    TILEB(1, t + 1, B1, B0)
  }
#undef TILEB
#undef MMH
#undef LDB
#undef BAR
}

// ================== 2-phase BK=64 core, BM=256 x BN=128 (pv, R16 proven) ==================
template <int KSTEPS, int SPLIT_STEP>
DEVINL void gemm2p_core(const ushort_t* __restrict__ a1, const ushort_t* __restrict__ a2,
                        int lda, const ushort_t* __restrict__ bsrc, int ldb,
                        ushort_t* lds, int tid, f32x4 (&acc)[4][4]) {
  constexpr int BUF = 24576;   // elems per buffer (A 16384 + B 8192)
  constexpr int BOFF = 16384;  // B region offset (elems)
  constexpr int KM = KSTEPS - 1;
  const int lane = tid & 63, w = tid >> 6;
  const int wr = (w >> 1) * 64, wc = (w & 1) * 64;
  const int slog = (lane & 7) ^ ((lane >> 3) & 7);

  const int sl0 = ((lane >> 4) ^ (lane & 7)) * 8;
  const int sl1 = ((4 + (lane >> 4)) ^ (lane & 7)) * 8;
  const ushort_t* dsA0 = lds + (wr + (lane & 15)) * 64 + sl0;
  const ushort_t* dsA1 = lds + (wr + (lane & 15)) * 64 + sl1;
  const ushort_t* dsB0 = lds + BOFF + (wc + (lane & 15)) * 64 + sl0;
  const ushort_t* dsB1 = lds + BOFF + (wc + (lane & 15)) * 64 + sl1;

  const size_t ldaS = (size_t)lda, ldbS = (size_t)ldb;
  const ushort_t* gA1 = a1 + (size_t)(w * 16 + (lane >> 3)) * ldaS + slog * 8;
  const ushort_t* gA2 = a2 + (size_t)(w * 16 + (lane >> 3)) * ldaS + slog * 8;
  const ushort_t* gB  = bsrc + (size_t)(w * 8 + (lane >> 3)) * ldbS + slog * 8;
  ushort_t* dA = lds + (w * 16) * 64;
  ushort_t* dB = lds + BOFF + (w * 8) * 64;

  auto stA = [&](int bb, int ks, int h) {
    const ushort_t* base = ((SPLIT_STEP >= KSTEPS) || (ks < SPLIT_STEP)) ? gA1 : gA2;
    const ushort_t* s = base + (ks & (SPLIT_STEP - 1)) * 64 + (size_t)(h * 128) * ldaS;
    ushort_t* d = dA + bb * BUF + h * 8192;
    gload_lds16(s, d);
    gload_lds16(s + 8 * ldaS, d + 512);
  };
  auto stB = [&](int bb, int ks, int h) {
    const ushort_t* s = gB + ks * 64 + (size_t)(h * 64) * ldbS;
    gload_lds16(s, dB + bb * BUF + h * 4096);
  };

#define BAR asm volatile("s_barrier" ::: "memory")
#define MM2(J)                                                       \
  __builtin_amdgcn_s_setprio(1);                                     \
  _Pragma("unroll")                                                  \
  for (int i = 0; i < 4; ++i) {                                      \
    acc[i][(J)]     = mfma16h(rA[i][0], Bc0, acc[i][(J)]);           \
    acc[i][(J)]     = mfma16h(rA[i][1], Bc1, acc[i][(J)]);           \
    acc[i][(J) + 1] = mfma16h(rA[i][0], Bc2, acc[i][(J) + 1]);       \
    acc[i][(J) + 1] = mfma16h(rA[i][1], Bc3, acc[i][(J) + 1]);       \
  }                                                                  \
  __builtin_amdgcn_s_setprio(0);
#define TILE2(BB, T) {                                               \
  const int ksB = ((T) + 1) & KM;                                    \
  const int ksA = ((T) + 2) & KM;                                    \
  const ushort_t* rA0 = dsA0 + (BB) * BUF;                           \
  const ushort_t* rA1 = dsA1 + (BB) * BUF;                           \
  const ushort_t* rB0 = dsB0 + (BB) * BUF;                           \
  const ushort_t* rB1 = dsB1 + (BB) * BUF;                           \
  f16x8 rA[4][2];                                                    \
  f16x8 Bc0, Bc1, Bc2, Bc3;                                          \
  _Pragma("unroll")                                                  \
  for (int i = 0; i < 4; ++i) {                                      \
    rA[i][0] = *(const f16x8*)(rA0 + i * 1024);                      \
    rA[i][1] = *(const f16x8*)(rA1 + i * 1024);                      \
  }                                                                  \
  Bc0 = *(const f16x8*)(rB0);                                        \
  Bc1 = *(const f16x8*)(rB1);                                        \
  Bc2 = *(const f16x8*)(rB0 + 1024);                                 \
  Bc3 = *(const f16x8*)(rB1 + 1024);                                 \
  stB(BB ^ 1, ksB, 0); stB(BB ^ 1, ksB, 1);                          \
  BAR; MM2(0) BAR;                                                   \
  Bc0 = *(const f16x8*)(rB0 + 2048);                                 \
  Bc1 = *(const f16x8*)(rB1 + 2048);                                 \
  Bc2 = *(const f16x8*)(rB0 + 3072);                                 \
  Bc3 = *(const f16x8*)(rB1 + 3072);                                 \
  stA(BB, ksA, 0); stA(BB, ksA, 1);                                  \
  BAR; MM2(2)                                                        \
  asm volatile("s_waitcnt vmcnt(4)" ::: "memory");                   \
  BAR;                                                               \
}

  stA(0, 0, 0); stA(0, 0, 1);
  stB(0, 0, 0); stB(0, 0, 1);
  stA(1, 1 & KM, 0); stA(1, 1 & KM, 1);
  asm volatile("s_waitcnt vmcnt(4)" ::: "memory");
  BAR;

  for (int t = 0; t < KSTEPS; t += 2) {
    TILE2(0, t)
    TILE2(1, t + 1)
  }
#undef TILE2
#undef MM2
#undef BAR
}

// ---------- kernel 1: t/v/a -> plain fp16 x + transposed xT ----------
__global__ __launch_bounds__(256) void split_x_kernel(
    const float* __restrict__ v, const float* __restrict__ t, const float* __restrict__ a,
    ushort_t* __restrict__ xh, ushort_t* __restrict__ xT) {
  __shared__ ushort_t tile[64][65];
  int mod = blockIdx.z;
  const float* src = (mod == 0) ? v : (mod == 1 ? t : a);
  int b = blockIdx.y;
  int s0 = (blockIdx.x >> 4) * 64;
  int f0 = (blockIdx.x & 15) * 64;
  int tid = threadIdx.x;
  ushort_t* xp = xh + mod * NX;
  ushort_t* xt = xT + mod * NX;
  int fl = (tid & 15) * 4;
#pragma unroll
  for (int r = 0; r < 4; ++r) {
    int sl = (tid >> 4) + r * 16;
    int row = b * S + s0 + sl;
    float4 x = *(const float4*)(src + (size_t)row * F + f0 + fl);
    ushort_t h0 = f2h(x.x), h1 = f2h(x.y), h2 = f2h(x.z), h3 = f2h(x.w);
    *(ushort4*)(xp + (size_t)row * F + f0 + fl) = make_ushort4(h0, h1, h2, h3);
    tile[sl][fl] = h0; tile[sl][fl + 1] = h1; tile[sl][fl + 2] = h2; tile[sl][fl + 3] = h3;
  }
  __syncthreads();
#pragma unroll
  for (int r = 0; r < 4; ++r) {
    int flr = (tid >> 4) + r * 16;
    int sl4 = (tid & 15) * 4;
    ushort4 o = make_ushort4(tile[sl4][flr], tile[sl4 + 1][flr],
                             tile[sl4 + 2][flr], tile[sl4 + 3][flr]);
    size_t tidx = ((size_t)(b * F + f0 + flr)) * S + s0 + sl4;
    *(ushort4*)(xt + tidx) = o;
  }
}

// ---------- kernel 2: W (2048x1024) -> WT plain fp16 (1024 rows x K=2048) ----------
__global__ __launch_bounds__(256) void split_w_kernel(
    const float* __restrict__ w0, const float* __restrict__ w1, const float* __restrict__ w2,
    ushort_t* __restrict__ wtpack) {
  __shared__ ushort_t th[64][65];
  int br = blockIdx.z;
  const float* w = (br == 0) ? w0 : (br == 1 ? w1 : w2);
  int g0 = blockIdx.x * 64;
  int f0 = blockIdx.y * 64;
  int tid = threadIdx.x;
  int gl = (tid & 15) * 4;
#pragma unroll
  for (int r = 0; r < 4; ++r) {
    int fl = (tid >> 4) + r * 16;
    float4 x = *(const float4*)(w + (size_t)(f0 + fl) * F + g0 + gl);
    th[fl][gl] = f2h(x.x); th[fl][gl + 1] = f2h(x.y);
    th[fl][gl + 2] = f2h(x.z); th[fl][gl + 3] = f2h(x.w);
  }
  __syncthreads();
  ushort_t* op = wtpack + br * NW;
#pragma unroll
  for (int r = 0; r < 4; ++r) {
    int glr = (tid >> 4) + r * 16;
    int fl4 = (tid & 15) * 4;
    size_t o = (size_t)(g0 + glr) * (2 * F) + f0 + fl4;
    *(ushort4*)(op + o) = make_ushort4(th[fl4][glr], th[fl4 + 1][glr],
                                       th[fl4 + 2][glr], th[fl4 + 3][glr]);
  }
}

// ---------- kernel 3: Feat = tanh(concat(x1,x2) @ W + b), fp16 out ----------
// B-in-register core; 768 blocks = 3.0 balanced rounds; 64 KB LDS.
__global__ __launch_bounds__(512, 2) void feat_gemm_kernel(
    const ushort_t* __restrict__ xh, const ushort_t* __restrict__ wtpack,
    const float* __restrict__ b0, const float* __restrict__ b1, const float* __restrict__ b2,
    ushort_t* __restrict__ fpack) {
  constexpr int M1[3] = {1, 1, 2};   // t, t, a
  constexpr int M2[3] = {0, 2, 0};   // v, a, v
  __shared__ __attribute__((aligned(16))) ushort_t lds[2 * 16384];   // 64 KB (A only)
  int br = blockIdx.z;
  int lin = blockIdx.x;              // 0..255
  // XCD-chunked: lin&7 = XCD; each XCD owns 4 fixed A-panels (R3 lever).
  int gm0 = ((lin & 7) * 4 + ((lin >> 3) & 3)) * 256;
  int gn0 = (lin >> 5) * 128;
  int tid = threadIdx.x, lane = tid & 63, w = tid >> 6;
  const ushort_t* a1 = xh + M1[br] * NX + (size_t)gm0 * F;
  const ushort_t* a2 = xh + M2[br] * NX + (size_t)gm0 * F;
  const ushort_t* bb = wtpack + br * NW + (size_t)gn0 * (2 * F);
  f32x4 acc[4][4] = {};
  gemm_breg_core<32, 16>(a1, a2, F, bb, 2 * F, lds, tid, acc);
  const float* bias = (br == 0) ? b0 : (br == 1 ? b1 : b2);
  ushort_t* op = fpack + br * NX;
  int wr = (w >> 1) * 64, wc = (w & 1) * 64;
#pragma unroll
  for (int i = 0; i < 4; ++i)
#pragma unroll
    for (int j = 0; j < 4; ++j)
#pragma unroll
      for (int r = 0; r < 4; ++r) {
        int row = gm0 + wr + i * 16 + (lane >> 4) * 4 + r;
        int col = gn0 + wc + j * 16 + (lane & 15);
        op[(size_t)row * F + col] = f2h(tanhf(acc[i][j][r] + bias[col]));
      }
}

// ---------- kernel 4: fused scores+softmax -> P fp16 (R13, unchanged) ----------
__global__ __launch_bounds__(512, 2) void attn_scores_kernel(
    const ushort_t* __restrict__ xh, const ushort_t* __restrict__ fpack,
    ushort_t* __restrict__ pbuf) {
  constexpr int QM[3] = {2, 0, 1};   // a, v, t
  constexpr int BUFE = 20480;        // elems: A 128x32=4096, B 512x32=16384
  constexpr int BOFFE = 4096;
  __shared__ __attribute__((aligned(16))) ushort_t lds[3 * BUFE + 1024];  // +2KB red
  float* redm = (float*)(lds + 3 * BUFE);   // [4 wn][128 rows]
  int z = blockIdx.z;
  int br = z >> 4, b = z & 15;
  int gm0 = blockIdx.x * 128;
  int tid = threadIdx.x, lane = tid & 63, w = tid >> 6;
  int wm = w >> 2, wn = w & 3;
  int wr = wm * 64, wc = wn * 128;
  const ushort_t* qa = xh + QM[br] * NX + (size_t)(b * S + gm0) * F;
  const ushort_t* kb = fpack + br * NX + (size_t)(b * S) * F;   // all 512 key rows

  const int scol = (((lane & 3) ^ ((lane >> 3) & 3)) * 8);
  const int foff = (lane & 15) * 32 + (((lane >> 4) ^ ((lane >> 1) & 3)) * 8);

  auto stA = [&](int sb, int ks) {
    const ushort_t* s = qa + (size_t)(w * 16 + (lane >> 2)) * F + ks * 32 + scol;
    gload_lds16(s, lds + sb * BUFE + w * 512);
  };
  auto stB = [&](int sb, int ks) {
#pragma unroll
    for (int g = 0; g < 4; ++g) {
      const ushort_t* s = kb + (size_t)(w * 64 + g * 16 + (lane >> 2)) * F + ks * 32 + scol;
      gload_lds16(s, lds + sb * BUFE + BOFFE + w * 2048 + g * 512);
    }
  };

  f32x4 acc[4][8] = {};
  stA(0, 0); stB(0, 0);
  stA(1, 1); stB(1, 1);
  asm volatile("s_waitcnt vmcnt(5)" ::: "memory");
  asm volatile("s_barrier" ::: "memory");

  for (int t = 0; t < 32; ++t) {
    const int cb = t % 3, sb = (t + 2) % 3;
    const int ks = (t + 2) & 31;
    stA(sb, ks); stB(sb, ks);
    const ushort_t* L = lds + cb * BUFE;
    f16x8 rA[4], rB[8];
#pragma unroll
    for (int i = 0; i < 4; ++i) rA[i] = *(const f16x8*)(L + (wr + i * 16) * 32 + foff);
#pragma unroll
    for (int j = 0; j < 8; ++j)
      rB[j] = *(const f16x8*)(L + BOFFE + (wc + j * 16) * 32 + foff);
    __builtin_amdgcn_s_setprio(1);
#pragma unroll
    for (int j = 0; j < 8; ++j)
#pragma unroll
      for (int i = 0; i < 4; ++i) acc[i][j] = mfma16h(rA[i], rB[j], acc[i][j]);
    __builtin_amdgcn_s_setprio(0);
    asm volatile("s_waitcnt vmcnt(5)" ::: "memory");
    asm volatile("s_barrier" ::: "memory");
  }

  // ---- softmax epilogue over the 512 cols ----
  float mx[4][4];
#pragma unroll
  for (int i = 0; i < 4; ++i)
#pragma unroll
    for (int r = 0; r < 4; ++r) {
      float m = acc[i][0][r];
#pragma unroll
      for (int j = 1; j < 8; ++j) m = fmaxf(m, acc[i][j][r]);
#pragma unroll
      for (int d = 1; d < 16; d <<= 1) m = fmaxf(m, __shfl_xor(m, d));
      mx[i][r] = m;
    }
  if ((lane & 15) == 0) {
#pragma unroll
    for (int i = 0; i < 4; ++i)
#pragma unroll
      for (int r = 0; r < 4; ++r)
        redm[wn * 128 + wr + i * 16 + (lane >> 4) * 4 + r] = mx[i][r];
  }
  __syncthreads();
  float inv[4][4];
#pragma unroll
  for (int i = 0; i < 4; ++i)
#pragma unroll
    for (int r = 0; r < 4; ++r) {
      int row = wr + i * 16 + (lane >> 4) * 4 + r;
      float fm = fmaxf(fmaxf(redm[row], redm[128 + row]),
                       fmaxf(redm[256 + row], redm[384 + row]));
      float s = 0.f;
#pragma unroll
      for (int j = 0; j < 8; ++j) {
        float e = expf(acc[i][j][r] - fm);
        acc[i][j][r] = e;
        s += e;
      }
#pragma unroll
      for (int d = 1; d < 16; d <<= 1) s += __shfl_xor(s, d);
      inv[i][r] = s;
    }
  __syncthreads();
  if ((lane & 15) == 0) {
#pragma unroll
    for (int i = 0; i < 4; ++i)
#pragma unroll
      for (int r = 0; r < 4; ++r)
        redm[wn * 128 + wr + i * 16 + (lane >> 4) * 4 + r] = inv[i][r];
  }
  __syncthreads();
  ushort_t* pout = pbuf + (size_t)z * S * S;
#pragma unroll
  for (int i = 0; i < 4; ++i)
#pragma unroll
    for (int r = 0; r < 4; ++r) {
      int row = wr + i * 16 + (lane >> 4) * 4 + r;
      float fs = (redm[row] + redm[128 + row]) + (redm[256 + row] + redm[384 + row]);
      float fi = 1.0f / fs;
#pragma unroll
      for (int j = 0; j < 8; ++j) {
        int col = wc + j * 16 + (lane & 15);
        pout[(size_t)(gm0 + row) * S + col] = f2h(acc[i][j][r] * fi);
      }
    }
}

// ---------- kernel 5: O = (p @ q) * feat, fp32 out (R16, unchanged) ----------
__global__ __launch_bounds__(512, 2) void pv_gemm_kernel(
    const ushort_t* __restrict__ p, const ushort_t* __restrict__ xT,
    const ushort_t* __restrict__ fpack, float* __restrict__ out) {
  constexpr int QM[3] = {2, 0, 1};
  __shared__ __attribute__((aligned(16))) ushort_t lds[2 * 24576];   // 96 KB
  int z = blockIdx.z;
  int br = z >> 4, b = z & 15;
  int xblk = blockIdx.x;             // 0..15
  int gm0 = (xblk & 1) * 256;
  int gn0 = (xblk >> 1) * 128;
  int tid = threadIdx.x, lane = tid & 63, w = tid >> 6;
  const ushort_t* pa = p + (size_t)z * S * S + (size_t)gm0 * S;
  const ushort_t* qt = xT + QM[br] * NX + (size_t)b * F * S + (size_t)gn0 * S;  // [f][s]
  f32x4 acc[4][4] = {};
  gemm2p_core<8, 8>(pa, pa, S, qt, S, lds, tid, acc);
  const ushort_t* fp = fpack + br * NX;
  int wr = (w >> 1) * 64, wc = (w & 1) * 64;
#pragma unroll
  for (int i = 0; i < 4; ++i)
#pragma unroll
    for (int j = 0; j < 4; ++j)
#pragma unroll
      for (int r = 0; r < 4; ++r) {
        int row = gm0 + wr + i * 16 + (lane >> 4) * 4 + r;
        int col = gn0 + wc + j * 16 + (lane & 15);
        float fe = h2f(fp[(size_t)(b * S + row) * F + col]);
        out[(size_t)(b * S + row) * (3 * F) + br * F + col] = acc[i][j][r] * fe;
      }
}

extern "C" void kernel_launch(void* const* d_in, const int* in_sizes, int n_in,
                              void* d_out, int out_size, void* d_ws, size_t ws_size,
                              hipStream_t stream) {
  (void)in_sizes; (void)n_in; (void)out_size; (void)ws_size;
  const float* v = (const float*)d_in[0];
  const float* t = (const float*)d_in[1];
  const float* a = (const float*)d_in[2];
  const float* W_tv = (const float*)d_in[3];
  const float* b_tv = (const float*)d_in[4];
  const float* W_ta = (const float*)d_in[5];
  const float* b_ta = (const float*)d_in[6];
  const float* W_av = (const float*)d_in[7];
  const float* b_av = (const float*)d_in[8];
  float* out = (float*)d_out;

  // ws layout (~190 MB total)
  ushort_t* xh = (ushort_t*)d_ws;               // 3 * NX (fp16 plain)
  ushort_t* xT = xh + 3 * NX;                   // 3 * NX (fp16 plain, [f][s])
  ushort_t* wtpack = xT + 3 * NX;               // 3 * NW (fp16 plain)
  ushort_t* fpack = wtpack + 3 * NW;            // 3 * NX (fp16 plain)
  ushort_t* pbuf = fpack + 3 * NX;              // 3*B*S*S (fp16)

  split_x_kernel<<<dim3(128, 16, 3), 256, 0, stream>>>(v, t, a, xh, xT);
  split_w_kernel<<<dim3(16, 32, 3), 256, 0, stream>>>(W_tv, W_ta, W_av, wtpack);
  feat_gemm_kernel<<<dim3(256, 1, 3), 512, 0, stream>>>(xh, wtpack,
                                                        b_tv, b_ta, b_av, fpack);
  attn_scores_kernel<<<dim3(4, 1, 48), 512, 0, stream>>>(xh, fpack, pbuf);
  pv_gemm_kernel<<<dim3(16, 1, 48), 512, 0, stream>>>(pbuf, xT, fpack, out);
}

// Round 18
// 270.804 us; speedup vs baseline: 1.5194x; 1.5194x over previous
//
#include <hip/hip_runtime.h>

typedef unsigned short ushort_t;
typedef _Float16 f16x8 __attribute__((ext_vector_type(8)));
typedef float f32x4 __attribute__((ext_vector_type(4)));
typedef unsigned short u16x8 __attribute__((ext_vector_type(8)));

#define DEVINL __device__ __forceinline__

constexpr int B = 16, S = 512, F = 1024;
constexpr int M_ROWS = B * S;                    // 8192
constexpr size_t NX = (size_t)M_ROWS * F;        // 8,388,608 elems per modality
constexpr size_t NW = (size_t)F * (2 * F);       // 2,097,152 elems per branch

// ---------- fp16 helpers ----------
DEVINL ushort_t f2h(float f) { return __builtin_bit_cast(ushort_t, (_Float16)f); }
DEVINL float h2f(ushort_t h) { return (float)__builtin_bit_cast(_Float16, h); }

// ---------- async global->LDS (16B per lane) ----------
DEVINL void gload_lds16(const void* g, void* l) {
  __builtin_amdgcn_global_load_lds(
      (__attribute__((address_space(1))) void*)(g),
      (__attribute__((address_space(3))) void*)(l), 16, 0, 0);
}

DEVINL f32x4 mfma16h(f16x8 a, f16x8 b, f32x4 c) {
  return __builtin_amdgcn_mfma_f32_16x16x32_f16(a, b, c, 0, 0, 0);
}

// ================== 2-phase BK=64 fp16 GEMM core, BM=256 x BN=128 ==================
// R16-proven. 8 waves 4M x 2N, wave-tile 64x64 = acc[4][4], BK=64.
// LDS: 2 buffers x {A[256][64], B[128][64]} = 96 KB. Row = 128B = 8 slots,
// slot XOR-swizzled by (row&7) on BOTH staging source and ds_read (rule 21).
// Per tile: 2 phases x {reads | stage | barrier | 16 MFMA | barrier};
// ph0 stages B(t+1)->buf^1 (2 gloads), ph1 stages A(t+2)->buf A (4 gloads);
// tile-end vmcnt(4) leaves exactly A(t+2) in flight (counted, never 0 - T4).
// ALL staging via global_load_lds (hand-counted vmcnt); R17 lesson: mixing
// compiler-tracked register loads with manual vmcnt makes the compiler
// insert conservative drains every tile (feat 134->276 us). Don't hybridize.
// NOTE (R8): never raise __launch_bounds__ min-waves — (512,4) caps VGPR at
// 64 and spills the accumulator (3 GB scratch, 5x).
template <int KSTEPS, int SPLIT_STEP>
DEVINL void gemm2p_core(const ushort_t* __restrict__ a1, const ushort_t* __restrict__ a2,
                        int lda, const ushort_t* __restrict__ bsrc, int ldb,
                        ushort_t* lds, int tid, f32x4 (&acc)[4][4]) {
  constexpr int BUF = 24576;   // elems per buffer (A 16384 + B 8192)
  constexpr int BOFF = 16384;  // B region offset (elems)
  constexpr int KM = KSTEPS - 1;
  const int lane = tid & 63, w = tid >> 6;
  const int wr = (w >> 1) * 64, wc = (w & 1) * 64;
  const int slog = (lane & 7) ^ ((lane >> 3) & 7);   // swizzled k-slot (staging)

  // hoisted ds_read bases (row + swizzled slot, k-subtile 0/1)
  const int sl0 = ((lane >> 4) ^ (lane & 7)) * 8;
  const int sl1 = ((4 + (lane >> 4)) ^ (lane & 7)) * 8;
  const ushort_t* dsA0 = lds + (wr + (lane & 15)) * 64 + sl0;
  const ushort_t* dsA1 = lds + (wr + (lane & 15)) * 64 + sl1;
  const ushort_t* dsB0 = lds + BOFF + (wc + (lane & 15)) * 64 + sl0;
  const ushort_t* dsB1 = lds + BOFF + (wc + (lane & 15)) * 64 + sl1;

  // hoisted gload bases
  const size_t ldaS = (size_t)lda, ldbS = (size_t)ldb;
  const ushort_t* gA1 = a1 + (size_t)(w * 16 + (lane >> 3)) * ldaS + slog * 8;
  const ushort_t* gA2 = a2 + (size_t)(w * 16 + (lane >> 3)) * ldaS + slog * 8;
  const ushort_t* gB  = bsrc + (size_t)(w * 8 + (lane >> 3)) * ldbS + slog * 8;
  ushort_t* dA = lds + (w * 16) * 64;          // + bb*BUF + h*8192; HW adds lane*16B
  ushort_t* dB = lds + BOFF + (w * 8) * 64;    // + bb*BUF + h*4096

  auto stA = [&](int bb, int ks, int h) {      // 128 rows per half, 2 gloads/wave
    const ushort_t* base = ((SPLIT_STEP >= KSTEPS) || (ks < SPLIT_STEP)) ? gA1 : gA2;
    const ushort_t* s = base + (ks & (SPLIT_STEP - 1)) * 64 + (size_t)(h * 128) * ldaS;
    ushort_t* d = dA + bb * BUF + h * 8192;
    gload_lds16(s, d);
    gload_lds16(s + 8 * ldaS, d + 512);
  };
  auto stB = [&](int bb, int ks, int h) {      // 64 rows per half, 1 gload/wave
    const ushort_t* s = gB + ks * 64 + (size_t)(h * 64) * ldbS;
    gload_lds16(s, dB + bb * BUF + h * 4096);
  };

#define BAR asm volatile("s_barrier" ::: "memory")
#define MM2(J)                                                       \
  __builtin_amdgcn_s_setprio(1);                                     \
  _Pragma("unroll")                                                  \
  for (int i = 0; i < 4; ++i) {                                      \
    acc[i][(J)]     = mfma16h(rA[i][0], Bc0, acc[i][(J)]);           \
    acc[i][(J)]     = mfma16h(rA[i][1], Bc1, acc[i][(J)]);           \
    acc[i][(J) + 1] = mfma16h(rA[i][0], Bc2, acc[i][(J) + 1]);       \
    acc[i][(J) + 1] = mfma16h(rA[i][1], Bc3, acc[i][(J) + 1]);       \
  }                                                                  \
  __builtin_amdgcn_s_setprio(0);
#define TILE2(BB, T) {                                               \
  const int ksB = ((T) + 1) & KM;                                    \
  const int ksA = ((T) + 2) & KM;                                    \
  const ushort_t* rA0 = dsA0 + (BB) * BUF;                           \
  const ushort_t* rA1 = dsA1 + (BB) * BUF;                           \
  const ushort_t* rB0 = dsB0 + (BB) * BUF;                           \
  const ushort_t* rB1 = dsB1 + (BB) * BUF;                           \
  f16x8 rA[4][2];                                                    \
  f16x8 Bc0, Bc1, Bc2, Bc3;                                          \
  _Pragma("unroll")                                                  \
  for (int i = 0; i < 4; ++i) {                                      \
    rA[i][0] = *(const f16x8*)(rA0 + i * 1024);                      \
    rA[i][1] = *(const f16x8*)(rA1 + i * 1024);                      \
  }                                                                  \
  Bc0 = *(const f16x8*)(rB0);                                        \
  Bc1 = *(const f16x8*)(rB1);                                        \
  Bc2 = *(const f16x8*)(rB0 + 1024);                                 \
  Bc3 = *(const f16x8*)(rB1 + 1024);                                 \
  stB(BB ^ 1, ksB, 0); stB(BB ^ 1, ksB, 1);                          \
  BAR; MM2(0) BAR;                                                   \
  Bc0 = *(const f16x8*)(rB0 + 2048);                                 \
  Bc1 = *(const f16x8*)(rB1 + 2048);                                 \
  Bc2 = *(const f16x8*)(rB0 + 3072);                                 \
  Bc3 = *(const f16x8*)(rB1 + 3072);                                 \
  stA(BB, ksA, 0); stA(BB, ksA, 1);                                  \
  BAR; MM2(2)                                                        \
  asm volatile("s_waitcnt vmcnt(4)" ::: "memory");                   \
  BAR;                                                               \
}

  // prologue: A(0), B(0), A(1) -> vmcnt(4) leaves A(1) in flight (counted)
  stA(0, 0, 0); stA(0, 0, 1);
  stB(0, 0, 0); stB(0, 0, 1);
  stA(1, 1 & KM, 0); stA(1, 1 & KM, 1);
  asm volatile("s_waitcnt vmcnt(4)" ::: "memory");
  BAR;

  for (int t = 0; t < KSTEPS; t += 2) {
    TILE2(0, t)
    TILE2(1, t + 1)
  }
#undef TILE2
#undef MM2
#undef BAR
}

// ---------- kernel 1: t/v/a -> plain fp16 x + transposed xT ----------
__global__ __launch_bounds__(256) void split_x_kernel(
    const float* __restrict__ v, const float* __restrict__ t, const float* __restrict__ a,
    ushort_t* __restrict__ xh, ushort_t* __restrict__ xT) {
  __shared__ ushort_t tile[64][65];
  int mod = blockIdx.z;
  const float* src = (mod == 0) ? v : (mod == 1 ? t : a);
  int b = blockIdx.y;
  int s0 = (blockIdx.x >> 4) * 64;
  int f0 = (blockIdx.x & 15) * 64;
  int tid = threadIdx.x;
  ushort_t* xp = xh + mod * NX;
  ushort_t* xt = xT + mod * NX;
  int fl = (tid & 15) * 4;
#pragma unroll
  for (int r = 0; r < 4; ++r) {
    int sl = (tid >> 4) + r * 16;
    int row = b * S + s0 + sl;
    float4 x = *(const float4*)(src + (size_t)row * F + f0 + fl);
    ushort_t h0 = f2h(x.x), h1 = f2h(x.y), h2 = f2h(x.z), h3 = f2h(x.w);
    *(ushort4*)(xp + (size_t)row * F + f0 + fl) = make_ushort4(h0, h1, h2, h3);
    tile[sl][fl] = h0; tile[sl][fl + 1] = h1; tile[sl][fl + 2] = h2; tile[sl][fl + 3] = h3;
  }
  __syncthreads();
#pragma unroll
  for (int r = 0; r < 4; ++r) {
    int flr = (tid >> 4) + r * 16;
    int sl4 = (tid & 15) * 4;
    ushort4 o = make_ushort4(tile[sl4][flr], tile[sl4 + 1][flr],
                             tile[sl4 + 2][flr], tile[sl4 + 3][flr]);
    size_t tidx = ((size_t)(b * F + f0 + flr)) * S + s0 + sl4;
    *(ushort4*)(xt + tidx) = o;
  }
}

// ---------- kernel 2: W (2048x1024) -> WT plain fp16 (1024 rows x K=2048) ----------
__global__ __launch_bounds__(256) void split_w_kernel(
    const float* __restrict__ w0, const float* __restrict__ w1, const float* __restrict__ w2,
    ushort_t* __restrict__ wtpack) {
  __shared__ ushort_t th[64][65];
  int br = blockIdx.z;
  const float* w = (br == 0) ? w0 : (br == 1 ? w1 : w2);
  int g0 = blockIdx.x * 64;
  int f0 = blockIdx.y * 64;
  int tid = threadIdx.x;
  int gl = (tid & 15) * 4;
#pragma unroll
  for (int r = 0; r < 4; ++r) {
    int fl = (tid >> 4) + r * 16;
    float4 x = *(const float4*)(w + (size_t)(f0 + fl) * F + g0 + gl);
    th[fl][gl] = f2h(x.x); th[fl][gl + 1] = f2h(x.y);
    th[fl][gl + 2] = f2h(x.z); th[fl][gl + 3] = f2h(x.w);
  }
  __syncthreads();
  ushort_t* op = wtpack + br * NW;
#pragma unroll
  for (int r = 0; r < 4; ++r) {
    int glr = (tid >> 4) + r * 16;
    int fl4 = (tid & 15) * 4;
    size_t o = (size_t)(g0 + glr) * (2 * F) + f0 + fl4;
    *(ushort4*)(op + o) = make_ushort4(th[fl4][glr], th[fl4 + 1][glr],
                                       th[fl4 + 2][glr], th[fl4 + 3][glr]);
  }
}

// ---------- kernel 3: Feat = tanh(concat(x1,x2) @ W + b), fp16 out ----------
// BM=256 x BN=128 -> 256 blocks/branch, 768 total = 3.0 balanced rounds.
__global__ __launch_bounds__(512, 2) void feat_gemm_kernel(
    const ushort_t* __restrict__ xh, const ushort_t* __restrict__ wtpack,
    const float* __restrict__ b0, const float* __restrict__ b1, const float* __restrict__ b2,
    ushort_t* __restrict__ fpack) {
  constexpr int M1[3] = {1, 1, 2};   // t, t, a
  constexpr int M2[3] = {0, 2, 0};   // v, a, v
  __shared__ __attribute__((aligned(16))) ushort_t lds[2 * 24576];   // 96 KB
  int br = blockIdx.z;
  int lin = blockIdx.x;              // 0..255
  // XCD-chunked: lin&7 = XCD (z*256 preserves mod-8); each XCD owns 4 fixed
  // A-panels shared by its 8 n-blocks (R3's proven FETCH lever).
  int gm0 = ((lin & 7) * 4 + ((lin >> 3) & 3)) * 256;
  int gn0 = (lin >> 5) * 128;
  int tid = threadIdx.x, lane = tid & 63, w = tid >> 6;
  const ushort_t* a1 = xh + M1[br] * NX + (size_t)gm0 * F;
  const ushort_t* a2 = xh + M2[br] * NX + (size_t)gm0 * F;
  const ushort_t* bb = wtpack + br * NW + (size_t)gn0 * (2 * F);
  f32x4 acc[4][4] = {};
  gemm2p_core<32, 16>(a1, a2, F, bb, 2 * F, lds, tid, acc);
  const float* bias = (br == 0) ? b0 : (br == 1 ? b1 : b2);
  ushort_t* op = fpack + br * NX;
  int wr = (w >> 1) * 64, wc = (w & 1) * 64;
#pragma unroll
  for (int i = 0; i < 4; ++i)
#pragma unroll
    for (int j = 0; j < 4; ++j)
#pragma unroll
      for (int r = 0; r < 4; ++r) {
        int row = gm0 + wr + i * 16 + (lane >> 4) * 4 + r;
        int col = gn0 + wc + j * 16 + (lane & 15);
        op[(size_t)row * F + col] = f2h(tanhf(acc[i][j][r] + bias[col]));
      }
}

// ---------- kernel 4: fused scores+softmax -> P fp16 (R13, unchanged) ----------
__global__ __launch_bounds__(512, 2) void attn_scores_kernel(
    const ushort_t* __restrict__ xh, const ushort_t* __restrict__ fpack,
    ushort_t* __restrict__ pbuf) {
  constexpr int QM[3] = {2, 0, 1};   // a, v, t
  constexpr int BUFE = 20480;        // elems: A 128x32=4096, B 512x32=16384
  constexpr int BOFFE = 4096;
  __shared__ __attribute__((aligned(16))) ushort_t lds[3 * BUFE + 1024];  // +2KB red
  float* redm = (float*)(lds + 3 * BUFE);   // [4 wn][128 rows]
  int z = blockIdx.z;
  int br = z >> 4, b = z & 15;
  int gm0 = blockIdx.x * 128;
  int tid = threadIdx.x, lane = tid & 63, w = tid >> 6;
  int wm = w >> 2, wn = w & 3;
  int wr = wm * 64, wc = wn * 128;
  const ushort_t* qa = xh + QM[br] * NX + (size_t)(b * S + gm0) * F;
  const ushort_t* kb = fpack + br * NX + (size_t)(b * S) * F;   // all 512 key rows

  const int scol = (((lane & 3) ^ ((lane >> 3) & 3)) * 8);
  const int foff = (lane & 15) * 32 + (((lane >> 4) ^ ((lane >> 1) & 3)) * 8);

  auto stA = [&](int sb, int ks) {
    const ushort_t* s = qa + (size_t)(w * 16 + (lane >> 2)) * F + ks * 32 + scol;
    gload_lds16(s, lds + sb * BUFE + w * 512);
  };
  auto stB = [&](int sb, int ks) {
#pragma unroll
    for (int g = 0; g < 4; ++g) {
      const ushort_t* s = kb + (size_t)(w * 64 + g * 16 + (lane >> 2)) * F + ks * 32 + scol;
      gload_lds16(s, lds + sb * BUFE + BOFFE + w * 2048 + g * 512);
    }
  };

  f32x4 acc[4][8] = {};
  stA(0, 0); stB(0, 0);
  stA(1, 1); stB(1, 1);
  asm volatile("s_waitcnt vmcnt(5)" ::: "memory");
  asm volatile("s_barrier" ::: "memory");

  for (int t = 0; t < 32; ++t) {
    const int cb = t % 3, sb = (t + 2) % 3;
    const int ks = (t + 2) & 31;                 // clamped tail: uniform vmcnt
    stA(sb, ks); stB(sb, ks);
    const ushort_t* L = lds + cb * BUFE;
    f16x8 rA[4], rB[8];
#pragma unroll
    for (int i = 0; i < 4; ++i) rA[i] = *(const f16x8*)(L + (wr + i * 16) * 32 + foff);
#pragma unroll
    for (int j = 0; j < 8; ++j)
      rB[j] = *(const f16x8*)(L + BOFFE + (wc + j * 16) * 32 + foff);
    __builtin_amdgcn_s_setprio(1);
#pragma unroll
    for (int j = 0; j < 8; ++j)
#pragma unroll
      for (int i = 0; i < 4; ++i) acc[i][j] = mfma16h(rA[i], rB[j], acc[i][j]);
    __builtin_amdgcn_s_setprio(0);
    asm volatile("s_waitcnt vmcnt(5)" ::: "memory");
    asm volatile("s_barrier" ::: "memory");
  }

  // ---- softmax epilogue over the 512 cols ----
  float mx[4][4];
#pragma unroll
  for (int i = 0; i < 4; ++i)
#pragma unroll
    for (int r = 0; r < 4; ++r) {
      float m = acc[i][0][r];
#pragma unroll
      for (int j = 1; j < 8; ++j) m = fmaxf(m, acc[i][j][r]);
#pragma unroll
      for (int d = 1; d < 16; d <<= 1) m = fmaxf(m, __shfl_xor(m, d));
      mx[i][r] = m;
    }
  if ((lane & 15) == 0) {
#pragma unroll
    for (int i = 0; i < 4; ++i)
#pragma unroll
      for (int r = 0; r < 4; ++r)
        redm[wn * 128 + wr + i * 16 + (lane >> 4) * 4 + r] = mx[i][r];
  }
  __syncthreads();
  float inv[4][4];
#pragma unroll
  for (int i = 0; i < 4; ++i)
#pragma unroll
    for (int r = 0; r < 4; ++r) {
      int row = wr + i * 16 + (lane >> 4) * 4 + r;
      float fm = fmaxf(fmaxf(redm[row], redm[128 + row]),
                       fmaxf(redm[256 + row], redm[384 + row]));
      float s = 0.f;
#pragma unroll
      for (int j = 0; j < 8; ++j) {
        float e = expf(acc[i][j][r] - fm);
        acc[i][j][r] = e;
        s += e;
      }
#pragma unroll
      for (int d = 1; d < 16; d <<= 1) s += __shfl_xor(s, d);
      inv[i][r] = s;
    }
  __syncthreads();     // all reads of max partials done before overwrite
  if ((lane & 15) == 0) {
#pragma unroll
    for (int i = 0; i < 4; ++i)
#pragma unroll
      for (int r = 0; r < 4; ++r)
        redm[wn * 128 + wr + i * 16 + (lane >> 4) * 4 + r] = inv[i][r];
  }
  __syncthreads();
  ushort_t* pout = pbuf + (size_t)z * S * S;
#pragma unroll
  for (int i = 0; i < 4; ++i)
#pragma unroll
    for (int r = 0; r < 4; ++r) {
      int row = wr + i * 16 + (lane >> 4) * 4 + r;
      float fs = (redm[row] + redm[128 + row]) + (redm[256 + row] + redm[384 + row]);
      float fi = 1.0f / fs;
#pragma unroll
      for (int j = 0; j < 8; ++j) {
        int col = wc + j * 16 + (lane & 15);
        pout[(size_t)(gm0 + row) * S + col] = f2h(acc[i][j][r] * fi);
      }
    }
}

// ---------- kernel 5: O = (p @ q) * feat, fp32 out (R16, unchanged) ----------
__global__ __launch_bounds__(512, 2) void pv_gemm_kernel(
    const ushort_t* __restrict__ p, const ushort_t* __restrict__ xT,
    const ushort_t* __restrict__ fpack, float* __restrict__ out) {
  constexpr int QM[3] = {2, 0, 1};
  __shared__ __attribute__((aligned(16))) ushort_t lds[2 * 24576];   // 96 KB
  int z = blockIdx.z;
  int br = z >> 4, b = z & 15;
  int xblk = blockIdx.x;             // 0..15
  int gm0 = (xblk & 1) * 256;
  int gn0 = (xblk >> 1) * 128;
  int tid = threadIdx.x, lane = tid & 63, w = tid >> 6;
  const ushort_t* pa = p + (size_t)z * S * S + (size_t)gm0 * S;
  const ushort_t* qt = xT + QM[br] * NX + (size_t)b * F * S + (size_t)gn0 * S;  // [f][s]
  f32x4 acc[4][4] = {};
  gemm2p_core<8, 8>(pa, pa, S, qt, S, lds, tid, acc);
  const ushort_t* fp = fpack + br * NX;
  int wr = (w >> 1) * 64, wc = (w & 1) * 64;
#pragma unroll
  for (int i = 0; i < 4; ++i)
#pragma unroll
    for (int j = 0; j < 4; ++j)
#pragma unroll
      for (int r = 0; r < 4; ++r) {
        int row = gm0 + wr + i * 16 + (lane >> 4) * 4 + r;
        int col = gn0 + wc + j * 16 + (lane & 15);
        float fe = h2f(fp[(size_t)(b * S + row) * F + col]);
        out[(size_t)(b * S + row) * (3 * F) + br * F + col] = acc[i][j][r] * fe;
      }
}

extern "C" void kernel_launch(void* const* d_in, const int* in_sizes, int n_in,
                              void* d_out, int out_size, void* d_ws, size_t ws_size,
                              hipStream_t stream) {
  (void)in_sizes; (void)n_in; (void)out_size; (void)ws_size;
  const float* v = (const float*)d_in[0];
  const float* t = (const float*)d_in[1];
  const float* a = (const float*)d_in[2];
  const float* W_tv = (const float*)d_in[3];
  const float* b_tv = (const float*)d_in[4];
  const float* W_ta = (const float*)d_in[5];
  const float* b_ta = (const float*)d_in[6];
  const float* W_av = (const float*)d_in[7];
  const float* b_av = (const float*)d_in[8];
  float* out = (float*)d_out;

  // ws layout (~190 MB total)
  ushort_t* xh = (ushort_t*)d_ws;               // 3 * NX (fp16 plain)
  ushort_t* xT = xh + 3 * NX;                   // 3 * NX (fp16 plain, [f][s])
  ushort_t* wtpack = xT + 3 * NX;               // 3 * NW (fp16 plain)
  ushort_t* fpack = wtpack + 3 * NW;            // 3 * NX (fp16 plain)
  ushort_t* pbuf = fpack + 3 * NX;              // 3*B*S*S (fp16)

  split_x_kernel<<<dim3(128, 16, 3), 256, 0, stream>>>(v, t, a, xh, xT);
  split_w_kernel<<<dim3(16, 32, 3), 256, 0, stream>>>(W_tv, W_ta, W_av, wtpack);
  feat_gemm_kernel<<<dim3(256, 1, 3), 512, 0, stream>>>(xh, wtpack,
                                                        b_tv, b_ta, b_av, fpack);
  attn_scores_kernel<<<dim3(4, 1, 48), 512, 0, stream>>>(xh, fpack, pbuf);
  pv_gemm_kernel<<<dim3(16, 1, 48), 512, 0, stream>>>(pbuf, xT, fpack, out);
}